// Round 10
// baseline (465.139 us; speedup 1.0000x reference)
//
#include <hip/hip_runtime.h>

typedef _Float16 h8  __attribute__((ext_vector_type(8)));
typedef _Float16 hh4 __attribute__((ext_vector_type(4)));
typedef float    f4  __attribute__((ext_vector_type(4)));

#define TT 1024
#define FF 64
#define NTH 512
#define GRP 8
#define NGRP (TT / GRP)   // 128
#define K2 2.8853900817779268f   // 2/ln2

// swizzle for x_s only: elem ^= (row&7)<<3
#define HSWZ(r, e) ((e) ^ (((r) & 7) << 3))

__device__ __forceinline__ float tanh0(float z) {
  float e = __builtin_amdgcn_exp2f(z * K2);
  return __builtin_fmaf(-2.0f, __builtin_amdgcn_rcpf(e + 1.0f), 1.0f);
}

#define MFMA __builtin_amdgcn_mfma_f32_16x16x32_f16
#define FENCE() __builtin_amdgcn_sched_barrier(0)

// One persistent block per 2 batch rows; 8 waves; wave wv owns hidden cols
// [wv*16,wv*16+16) of each gate. Batch rows at M-rows 0,4 (C: row=4lg+reg).
// h compact in LDS (broadcast reads for non-owner lanes).
// x@W is INTERLEAVED into the recurrent steps: group g's 8 steps carry
// group g+1's staging/bulk-MFMA/scatter as per-step extras. The bulk MFMAs
// have register operands only, so they issue inside the post-barrier LDS
// read-latency hole where the matrix pipe is idle. zx double-buffered.
__global__ __launch_bounds__(NTH, 2) void lstm_persist(
    const float* __restrict__ X, const float* __restrict__ W,
    const float* __restrict__ U, const float* __restrict__ bias,
    const float* __restrict__ Wfc, const float* __restrict__ bfcp,
    float* __restrict__ out)
{
  const int tid = threadIdx.x;
  const int wv = tid >> 6, ln = tid & 63;
  const int l15 = ln & 15, lg = ln >> 4;
  const int row0 = blockIdx.x * 2;
  const int ncol = wv * 16 + l15;

  __shared__ __align__(16) _Float16 h_s[2][384];       // rows 0,1 live; row2 scratch
  __shared__ __align__(16) _Float16 x_s[16 * 64];      // 2KB, row m = 2*tt + r (swizzled)
  __shared__ __align__(16) _Float16 zx_s[2][16 * 512]; // 2 x 16KB dbuf [m][ncol*4+gate]
  __shared__ float red[8][2];

  // ---- persistent weight fragments (fp16, k-map k = 32f + 8lg + e, shared by A&B) ----
  h8 uf[4][4], wf4[4][2];
  f4 bias4[4];
#pragma unroll
  for (int g = 0; g < 4; ++g) {
    const int n = g * 128 + ncol;
#pragma unroll
    for (int f = 0; f < 4; ++f) {
      h8 v;
#pragma unroll
      for (int e = 0; e < 8; ++e) v[e] = (_Float16)U[(32 * f + 8 * lg + e) * 512 + n];
      uf[g][f] = v;
    }
#pragma unroll
    for (int f = 0; f < 2; ++f) {
      h8 v;
#pragma unroll
      for (int e = 0; e < 8; ++e) v[e] = (_Float16)W[(32 * f + 8 * lg + e) * 512 + n];
      wf4[g][f] = v;
    }
    const float bv = bias[n];
    f4 b4 = {bv, bv, bv, bv};
    bias4[g] = b4;
  }
  const float wfc = Wfc[ncol];

  // h-fragment offsets: real for l15==0 (row0) / l15==4 (row1); others -> 0 (broadcast)
  int hofs[4];
#pragma unroll
  for (int f = 0; f < 4; ++f) {
    const int base = 32 * f + 8 * lg;
    hofs[f] = (l15 == 0) ? base : (l15 == 4) ? 128 + base : 0;
  }
  // bulk x-fragment offsets (x_s swizzled): A rows m = l15 (one M-tile of 16)
  int bxofs[2];
#pragma unroll
  for (int f = 0; f < 2; ++f)
    bxofs[f] = HSWZ(l15, l15 * 64 + 32 * f + 8 * lg);

  // zx per-step read: lane needs m=2S+lg at ncol*4; lg>=2 -> broadcast base
  const int zofs  = (lg < 2) ? (lg * 512 + ncol * 4) : 0;
  const int zwofs = ncol * 4;
  const int hwofs = (lg < 2) ? (lg * 128 + ncol) : (256 + ncol);  // scratch row lg>=2

  // x staging map (threads 0..255): thread -> (m = 2*tt + r, 4 consecutive k)
  const int sm = tid >> 4;          // m row (valid < 16)
  const int sk = (tid & 15) * 4;
  const int sxofs = HSWZ(sm, sm * 64 + sk);
  const size_t xbase = (size_t)(row0 + (sm & 1)) * (TT * FF) + (size_t)(sm >> 1) * FF + sk;

  // zero compact h (both buffers, incl. scratch rows)
  for (int i = tid; i < 2 * 384; i += NTH) ((_Float16*)h_s)[i] = (_Float16)0.0f;

  // ---- prologue: stage group-0 x, bulk zx[0], prefetch group-1 x ----
  f4 xg;
  h8 xa0, xa1;
  f4 b0, b1, b2, b3;
  if (tid < 256) {
    xg = *(const f4*)(X + xbase);
    hh4 pk;
#pragma unroll
    for (int j = 0; j < 4; ++j) pk[j] = (_Float16)xg[j];
    *(hh4*)(&x_s[sxofs]) = pk;
  }
  __syncthreads();
  xa0 = *(const h8*)(&x_s[bxofs[0]]);
  xa1 = *(const h8*)(&x_s[bxofs[1]]);
  b0 = MFMA(xa0, wf4[0][0], bias4[0], 0, 0, 0);
  b1 = MFMA(xa0, wf4[1][0], bias4[1], 0, 0, 0);
  b2 = MFMA(xa0, wf4[2][0], bias4[2], 0, 0, 0);
  b3 = MFMA(xa0, wf4[3][0], bias4[3], 0, 0, 0);
  b0 = MFMA(xa1, wf4[0][1], b0, 0, 0, 0);
  b1 = MFMA(xa1, wf4[1][1], b1, 0, 0, 0);
  b2 = MFMA(xa1, wf4[2][1], b2, 0, 0, 0);
  b3 = MFMA(xa1, wf4[3][1], b3, 0, 0, 0);
#pragma unroll
  for (int j = 0; j < 4; ++j) {
    hh4 p; p[0] = (_Float16)b0[j]; p[1] = (_Float16)b1[j];
           p[2] = (_Float16)b2[j]; p[3] = (_Float16)b3[j];
    *(hh4*)(&zx_s[0][(4 * lg + j) * 512 + zwofs]) = p;
  }
  if (tid < 256) xg = *(const f4*)(X + xbase + (size_t)GRP * FF);  // group-1 x
  float cc = 0.f;
  const f4 zq = {0.f, 0.f, 0.f, 0.f};
  __syncthreads();

#define STEP(S, CUR, NXT) {                                                   \
    const _Float16* hb = &h_s[CUR][0];                                        \
    h8 ha0 = *(const h8*)(hb + hofs[0]);                                      \
    h8 ha1 = *(const h8*)(hb + hofs[1]);                                      \
    h8 ha2 = *(const h8*)(hb + hofs[2]);                                      \
    h8 ha3 = *(const h8*)(hb + hofs[3]);                                      \
    hh4 q4 = *(const hh4*)(&zx_s[0][0] + zrb + zofs + (S) * 1024);            \
    /* bulk extras: register-operand MFMAs fill the LDS-latency hole */       \
    if ((S) == 1) xa0 = *(const h8*)(&x_s[bxofs[0]]);                         \
    if ((S) == 2) xa1 = *(const h8*)(&x_s[bxofs[1]]);                         \
    if ((S) == 2) { b0 = MFMA(xa0, wf4[0][0], bias4[0], 0, 0, 0);             \
                    b1 = MFMA(xa0, wf4[1][0], bias4[1], 0, 0, 0); }           \
    if ((S) == 3) { b2 = MFMA(xa0, wf4[2][0], bias4[2], 0, 0, 0);             \
                    b3 = MFMA(xa0, wf4[3][0], bias4[3], 0, 0, 0); }           \
    if ((S) == 4) { b0 = MFMA(xa1, wf4[0][1], b0, 0, 0, 0);                   \
                    b1 = MFMA(xa1, wf4[1][1], b1, 0, 0, 0); }                 \
    if ((S) == 5) { b2 = MFMA(xa1, wf4[2][1], b2, 0, 0, 0);                   \
                    b3 = MFMA(xa1, wf4[3][1], b3, 0, 0, 0); }                 \
    f4 a0 = MFMA(ha0, uf[0][0], zq, 0, 0, 0);                                 \
    a0 = MFMA(ha1, uf[0][1], a0, 0, 0, 0);                                    \
    a0 = MFMA(ha2, uf[0][2], a0, 0, 0, 0);                                    \
    a0 = MFMA(ha3, uf[0][3], a0, 0, 0, 0);                                    \
    float ti = tanh0(a0[0] + (float)q4[0]);                                   \
    FENCE();                                                                  \
    f4 a1 = MFMA(ha0, uf[1][0], zq, 0, 0, 0);                                 \
    a1 = MFMA(ha1, uf[1][1], a1, 0, 0, 0);                                    \
    a1 = MFMA(ha2, uf[1][2], a1, 0, 0, 0);                                    \
    a1 = MFMA(ha3, uf[1][3], a1, 0, 0, 0);                                    \
    float tf = tanh0(a1[0] + (float)q4[1]);                                   \
    FENCE();                                                                  \
    f4 a2 = MFMA(ha0, uf[2][0], zq, 0, 0, 0);                                 \
    a2 = MFMA(ha1, uf[2][1], a2, 0, 0, 0);                                    \
    a2 = MFMA(ha2, uf[2][2], a2, 0, 0, 0);                                    \
    a2 = MFMA(ha3, uf[2][3], a2, 0, 0, 0);                                    \
    float tg = tanh0(a2[0] + (float)q4[2]);                                   \
    cc = __builtin_fmaf(tf, cc, ti * tg);                                     \
    FENCE();                                                                  \
    f4 a3 = MFMA(ha0, uf[3][0], zq, 0, 0, 0);                                 \
    a3 = MFMA(ha1, uf[3][1], a3, 0, 0, 0);                                    \
    a3 = MFMA(ha2, uf[3][2], a3, 0, 0, 0);                                    \
    a3 = MFMA(ha3, uf[3][3], a3, 0, 0, 0);                                    \
    float to = tanh0(a3[0] + (float)q4[3]);                                   \
    float hv = to * tanh0(cc);                                                \
    h_s[NXT][hwofs] = (_Float16)hv;                                           \
    /* staging / scatter / prefetch extras (off the critical tanh path) */    \
    if ((S) == 0 && tid < 256) {                                              \
      hh4 pk;                                                                 \
      _Pragma("unroll")                                                       \
      for (int j = 0; j < 4; ++j) pk[j] = (_Float16)xg[j];                    \
      *(hh4*)(&x_s[sxofs]) = pk;                                              \
    }                                                                         \
    if ((S) == 3 && tid < 256) {                                              \
      int t2 = (grp + 2) * GRP; if (t2 >= TT) t2 = TT - GRP;                  \
      xg = *(const f4*)(X + xbase + (size_t)t2 * FF);                         \
    }                                                                         \
    if ((S) == 6) {                                                           \
      _Float16* zwp = &zx_s[0][0] + zwb + zwofs;                              \
      _Pragma("unroll")                                                       \
      for (int j = 0; j < 2; ++j) {                                           \
        hh4 p; p[0] = (_Float16)b0[j]; p[1] = (_Float16)b1[j];                \
               p[2] = (_Float16)b2[j]; p[3] = (_Float16)b3[j];                \
        *(hh4*)(zwp + (4 * lg + j) * 512) = p;                                \
      }                                                                       \
    }                                                                         \
    if ((S) == 7) {                                                           \
      _Float16* zwp = &zx_s[0][0] + zwb + zwofs;                              \
      _Pragma("unroll")                                                       \
      for (int j = 2; j < 4; ++j) {                                           \
        hh4 p; p[0] = (_Float16)b0[j]; p[1] = (_Float16)b1[j];                \
               p[2] = (_Float16)b2[j]; p[3] = (_Float16)b3[j];                \
        *(hh4*)(zwp + (4 * lg + j) * 512) = p;                                \
      }                                                                       \
    }                                                                         \
    __syncthreads();                                                          \
  }

#pragma unroll 1
  for (int grp = 0; grp < NGRP; ++grp) {
    const int zrb = (grp & 1) << 13;   // 8192 elems per zx buffer
    const int zwb = 8192 - zrb;
    STEP(0, 0, 1)
    STEP(1, 1, 0)
    STEP(2, 0, 1)
    STEP(3, 1, 0)
    STEP(4, 0, 1)
    STEP(5, 1, 0)
    STEP(6, 0, 1)
    STEP(7, 1, 0)
  }
#undef STEP

  // ---- epilogue: y[r] = h_last[r,:] @ Wfc + bfc  (h_last in buffer 0) ----
  float hw0 = (float)h_s[0][ncol];
  float hw1 = (float)h_s[0][128 + ncol];
  float p0 = hw0 * wfc;
  float p1 = hw1 * wfc;
#pragma unroll
  for (int m = 1; m < 16; m <<= 1) {
    p0 += __shfl_xor(p0, m, 16);
    p1 += __shfl_xor(p1, m, 16);
  }
  if (ln == 0) { red[wv][0] = p0; red[wv][1] = p1; }
  __syncthreads();
  if (tid < 2) {
    float y = bfcp[0];
#pragma unroll
    for (int w2 = 0; w2 < 8; ++w2) y += red[w2][tid];
    out[row0 + tid] = y;
  }
}

extern "C" void kernel_launch(void* const* d_in, const int* in_sizes, int n_in,
                              void* d_out, int out_size, void* d_ws, size_t ws_size,
                              hipStream_t stream) {
  const float* x   = (const float*)d_in[0];
  const float* W   = (const float*)d_in[1];
  const float* U   = (const float*)d_in[2];
  const float* b   = (const float*)d_in[3];
  const float* Wfc = (const float*)d_in[4];
  const float* bfc = (const float*)d_in[5];
  float* out = (float*)d_out;
  hipLaunchKernelGGL(lstm_persist, dim3(256), dim3(NTH), 0, stream,
                     x, W, U, b, Wfc, bfc, out);
}